// Round 12
// baseline (453.773 us; speedup 1.0000x reference)
//
#include <hip/hip_runtime.h>
#include <stdint.h>

// PCT forward: stem(conv1x1+BN+ReLU ×2) -> concat cls -> 4× [LNqkv-fused, attn, fc, LNff1-fused, ff2]
// B=8 C=256 N=1024 D=256 DK=16 DV=32 H=8 NB=4 P=1025, M_tok=8200

typedef unsigned short u16;
typedef unsigned int   u32;
typedef __bf16 bf16x8 __attribute__((ext_vector_type(8)));
typedef float  f32x4  __attribute__((ext_vector_type(4)));
typedef float  f32x16 __attribute__((ext_vector_type(16)));
typedef u32    u32x4  __attribute__((ext_vector_type(4)));

#define DEV static __device__ __forceinline__

DEV float b2f(u16 h){ u32 u = ((u32)h) << 16; return __builtin_bit_cast(float, u); }
DEV u16 f2b(float f){ u32 u = __builtin_bit_cast(u32, f); u32 r = (u + 0x7fffu + ((u >> 16) & 1u)) >> 16; return (u16)r; }
DEV float gelu_f(float x){ return 0.5f * x * (1.0f + erff(x * 0.7071067811865475f)); }
DEV u32 cvtpk(float lo, float hi){
  u32 w;
  asm("v_cvt_pk_bf16_f32 %0, %1, %2" : "=v"(w) : "v"(lo), "v"(hi));
  return w;
}
DEV float exp2_(float x){ float r; asm("v_exp_f32 %0, %1" : "=v"(r) : "v"(x)); return r; }

typedef void __attribute__((address_space(1)))* gas_t;
typedef void __attribute__((address_space(3)))* las_t;
DEV void cp16(const void* g, void* l){
  __builtin_amdgcn_global_load_lds((gas_t)(uintptr_t)g, (las_t)(uintptr_t)l, 16, 0, 0);
}

// ---------------- weight conversion f32 -> bf16 (with QKV concat, optional scale) ----------------
struct Seg { const float* src; u16* dst; int n; int period; int dstride; int block0; float scale; };
struct SegPack { Seg s[8]; };

__global__ __launch_bounds__(256) void k_convert(SegPack p){
  int bid = blockIdx.x;
  int si = 0;
  #pragma unroll
  for (int i = 1; i < 8; i++) if (bid >= p.s[i].block0) si = i;
  const Seg sg = p.s[si];
  int e0 = (bid - sg.block0) * 2048 + threadIdx.x * 8;
  #pragma unroll
  for (int k = 0; k < 8; k++){
    int e = e0 + k;
    if (e < sg.n) sg.dst[(e / sg.period) * sg.dstride + (e % sg.period)] = f2b(sg.src[e] * sg.scale);
  }
}

// ---------------- x [B,C,N] f32 -> xT [B,N,C] bf16 ----------------
__global__ __launch_bounds__(256) void k_transpose_x(const float* __restrict__ x, u16* __restrict__ xT){
  __shared__ float t[32][33];
  int b = blockIdx.z, ct = blockIdx.y, nt = blockIdx.x;
  int tx = threadIdx.x & 31, ty = threadIdx.x >> 5;
  const float* xp = x + ((size_t)b * 256 + ct * 32) * 1024 + nt * 32;
  #pragma unroll
  for (int k = 0; k < 4; k++) t[ty + 8*k][tx] = xp[(size_t)(ty + 8*k) * 1024 + tx];
  __syncthreads();
  u16* op = xT + ((size_t)b * 1024 + nt * 32) * 256 + ct * 32;
  #pragma unroll
  for (int k = 0; k < 4; k++) op[(size_t)(ty + 8*k) * 256 + tx] = f2b(t[tx][ty + 8*k]);
}

// ---------------- cls token row ----------------
__global__ void k_cls(const float* __restrict__ cls, float* __restrict__ h){
  int d = threadIdx.x;
  #pragma unroll
  for (int b = 0; b < 8; b++) h[(size_t)b * 1025 * 256 + d] = cls[d];
}

// ---------------- NT GEMM BMxBN (bf16 A), 4 waves (2x2), XCD-pinned 1D grid ----------------
// EPI: 1 bn+relu->bf16 | 2 bn+relu->f32 row-shifted | 3 f32 += | 5 f32 += (+bias)
template<int EPI, int BM, int BN>
__global__ __launch_bounds__(256) void k_gemmT(const u16* __restrict__ A, const u16* __restrict__ W,
    int M, int K, int E, float* __restrict__ outF, u16* __restrict__ outB,
    const float* __restrict__ a0, const float* __restrict__ a1,
    const float* __restrict__ a2, const float* __restrict__ a3){
  constexpr int MR = BM / 32, NR = BN / 32;
  __shared__ __align__(16) u16 As[BM * 64];
  __shared__ __align__(16) u16 Bs[BN * 64];
  const int MTILES = (M + BM - 1) / BM;
  const int MT8 = (MTILES + 7) >> 3;
  const int bid = blockIdx.x;
  const int xcd = bid & 7, rest = bid >> 3;
  const int mi = xcd + 8 * (rest % MT8);
  const int ni = rest / MT8;
  if (mi >= MTILES) return;
  const int tM = mi * BM, tN = ni * BN;
  const int tid = threadIdx.x;
  const int lane = tid & 63, wv = tid >> 6;
  const int wr = wv >> 1, wc = wv & 1;
  f32x4 acc[MR][NR];
  #pragma unroll
  for (int m = 0; m < MR; m++)
    #pragma unroll
    for (int n = 0; n < NR; n++)
      #pragma unroll
      for (int j = 0; j < 4; j++) acc[m][n][j] = 0.f;

  const int l8 = lane >> 3, lm = lane & 7;
  for (int k0 = 0; k0 < K; k0 += 64){
    __syncthreads();
    #pragma unroll
    for (int is = 0; is < BM / 32; is++){
      int row = is * 32 + wv * 8 + l8;
      int kg = lm ^ (row & 7);
      int ra = tM + row; ra = ra < M ? ra : M - 1;
      cp16(A + (size_t)ra * K + k0 + kg * 8, As + is * 2048 + wv * 512);
    }
    #pragma unroll
    for (int is = 0; is < BN / 32; is++){
      int row = is * 32 + wv * 8 + l8;
      int kg = lm ^ (row & 7);
      cp16(W + (size_t)(tN + row) * K + k0 + kg * 8, Bs + is * 2048 + wv * 512);
    }
    __syncthreads();
    #pragma unroll
    for (int kk = 0; kk < 2; kk++){
      bf16x8 af[MR], bfv[NR];
      #pragma unroll
      for (int m = 0; m < MR; m++){
        int row = wr * (BM/2) + m * 16 + (lane & 15);
        int kg = (kk * 4 + (lane >> 4)) ^ (row & 7);
        af[m] = *reinterpret_cast<const bf16x8*>(&As[row * 64 + kg * 8]);
      }
      #pragma unroll
      for (int n = 0; n < NR; n++){
        int row = wc * (BN/2) + n * 16 + (lane & 15);
        int kg = (kk * 4 + (lane >> 4)) ^ (row & 7);
        bfv[n] = *reinterpret_cast<const bf16x8*>(&Bs[row * 64 + kg * 8]);
      }
      #pragma unroll
      for (int m = 0; m < MR; m++)
        #pragma unroll
        for (int n = 0; n < NR; n++)
          acc[m][n] = __builtin_amdgcn_mfma_f32_16x16x32_bf16(af[m], bfv[n], acc[m][n], 0, 0, 0);
    }
  }
  #pragma unroll
  for (int n = 0; n < NR; n++){
    const int col = tN + wc * (BN/2) + n * 16 + (lane & 15);
    float scale = 0.f, shift = 0.f, bias = 0.f;
    if (EPI == 1 || EPI == 2){
      float gv = a0[col], bv = a1[col], mv = a2[col], vv = a3[col];
      scale = gv * rsqrtf(vv + 1e-5f);
      shift = bv - mv * scale;
    }
    if (EPI == 5) bias = a0[col];
    #pragma unroll
    for (int m = 0; m < MR; m++){
      const int row0 = tM + wr * (BM/2) + m * 16 + ((lane >> 4) << 2);
      #pragma unroll
      for (int j = 0; j < 4; j++){
        int r = row0 + j;
        if (r < M){
          float v = acc[m][n][j];
          if (EPI == 1){ v = v * scale + shift; v = v > 0.f ? v : 0.f; outB[(size_t)r * E + col] = f2b(v); }
          else if (EPI == 2){ v = v * scale + shift; v = v > 0.f ? v : 0.f; outF[(size_t)(r + (r >> 10) + 1) * 256 + col] = v; }
          else if (EPI == 3){ outF[(size_t)r * E + col] += v; }
          else { outF[(size_t)r * E + col] += v + bias; }
        }
      }
    }
  }
}

// ---------------- fused LN(h)+GEMM: A = LN(h[64 rows]) staged once as bf16, K=256 resident ----------------
// Parallel LN: thread owns quarter-row (16xfloat4), stats via 2 shfl_xor (4 lanes/row), no serial chain.
// EPI 4: (+bias,gelu)->bf16.  EPI 6: qkv split (Q->outB, K->kb dense, V->outB + vt transposed).
template<int EPI>
__global__ __launch_bounds__(256) void k_gln(const float* __restrict__ hA, const u16* __restrict__ W,
    int M, int E, const float* __restrict__ lg, const float* __restrict__ lb,
    float* __restrict__ outF, u16* __restrict__ outB, u16* __restrict__ outK,
    const float* __restrict__ a0){
  constexpr int BM = 64, BN = 128, MR = 2, NR = 4;
  __shared__ __align__(16) u16 As[64 * 256];
  __shared__ __align__(16) u16 Bs[BN * 64];
  const int MTILES = (M + BM - 1) / BM;
  const int MT8 = (MTILES + 7) >> 3;
  const int bid = blockIdx.x;
  const int xcd = bid & 7, rest = bid >> 3;
  const int mi = xcd + 8 * (rest % MT8);
  const int ni = rest / MT8;
  if (mi >= MTILES) return;
  const int tM = mi * BM, tN = ni * BN;
  const int tid = threadIdx.x;
  const int lane = tid & 63, wv = tid >> 6;
  const int wr = wv >> 1, wc = wv & 1;

  // ---- A staging: LN(h) -> bf16 LDS panel (full K=256) ----
  {
    const int r = tid >> 2, qd = tid & 3;
    int ra = tM + r; ra = ra < M ? ra : M - 1;
    const float* hrow = hA + (size_t)ra * 256 + qd * 64;
    float4 hv[16];
    #pragma unroll
    for (int c = 0; c < 16; c++) hv[c] = *reinterpret_cast<const float4*>(hrow + c * 4);
    float s = 0.f, q = 0.f;
    #pragma unroll
    for (int c = 0; c < 16; c++){
      s += (hv[c].x + hv[c].y) + (hv[c].z + hv[c].w);
      q += (hv[c].x*hv[c].x + hv[c].y*hv[c].y) + (hv[c].z*hv[c].z + hv[c].w*hv[c].w);
    }
    s += __shfl_xor(s, 1); s += __shfl_xor(s, 2);
    q += __shfl_xor(q, 1); q += __shfl_xor(q, 2);
    const float mean = s * (1.f/256.f);
    const float var  = q * (1.f/256.f) - mean * mean;
    const float rs = rsqrtf(var + 1e-5f);
    #pragma unroll
    for (int w = 0; w < 8; w++){
      u32x4 d;
      #pragma unroll
      for (int half = 0; half < 2; half++){
        const int c = 2 * w + half;
        const float4 g4 = *reinterpret_cast<const float4*>(lg + qd * 64 + c * 4);
        const float4 b4 = *reinterpret_cast<const float4*>(lb + qd * 64 + c * 4);
        float v0 = (hv[c].x - mean) * rs * g4.x + b4.x;
        float v1 = (hv[c].y - mean) * rs * g4.y + b4.y;
        float v2 = (hv[c].z - mean) * rs * g4.z + b4.z;
        float v3 = (hv[c].w - mean) * rs * g4.w + b4.w;
        d[half*2 + 0] = cvtpk(v0, v1);
        d[half*2 + 1] = cvtpk(v2, v3);
      }
      const int gL = (qd * 8 + w) ^ (r & 7);
      *reinterpret_cast<u32x4*>(&As[r * 256 + gL * 8]) = d;
    }
  }

  f32x4 acc[MR][NR];
  #pragma unroll
  for (int m = 0; m < MR; m++)
    #pragma unroll
    for (int n = 0; n < NR; n++)
      #pragma unroll
      for (int j = 0; j < 4; j++) acc[m][n][j] = 0.f;

  const int l8 = lane >> 3, lm = lane & 7;
  for (int k0 = 0; k0 < 256; k0 += 64){
    __syncthreads();                     // k0=0: also drains A ds_writes
    #pragma unroll
    for (int is = 0; is < NR; is++){
      int row = is * 32 + wv * 8 + l8;
      int kg = lm ^ (row & 7);
      cp16(W + (size_t)(tN + row) * 256 + k0 + kg * 8, Bs + is * 2048 + wv * 512);
    }
    __syncthreads();
    #pragma unroll
    for (int kk = 0; kk < 2; kk++){
      bf16x8 af[MR], bfv[NR];
      #pragma unroll
      for (int m = 0; m < MR; m++){
        int row = wr * 32 + m * 16 + (lane & 15);
        int gk = (k0 >> 3) + kk * 4 + (lane >> 4);   // global 16B-group 0..31
        int g = gk ^ (row & 7);
        af[m] = *reinterpret_cast<const bf16x8*>(&As[row * 256 + g * 8]);
      }
      #pragma unroll
      for (int n = 0; n < NR; n++){
        int row = wc * 64 + n * 16 + (lane & 15);
        int kg = (kk * 4 + (lane >> 4)) ^ (row & 7);
        bfv[n] = *reinterpret_cast<const bf16x8*>(&Bs[row * 64 + kg * 8]);
      }
      #pragma unroll
      for (int m = 0; m < MR; m++)
        #pragma unroll
        for (int n = 0; n < NR; n++)
          acc[m][n] = __builtin_amdgcn_mfma_f32_16x16x32_bf16(af[m], bfv[n], acc[m][n], 0, 0, 0);
    }
  }
  #pragma unroll
  for (int n = 0; n < NR; n++){
    const int col = tN + wc * 64 + n * 16 + (lane & 15);
    float bias = 0.f;
    if (EPI == 4) bias = a0[col];
    #pragma unroll
    for (int m = 0; m < MR; m++){
      const int row0 = tM + wr * 32 + m * 16 + ((lane >> 4) << 2);
      #pragma unroll
      for (int j = 0; j < 4; j++){
        int r = row0 + j;
        if (r < M){
          float v = acc[m][n][j];
          if (EPI == 4){ outB[(size_t)r * E + col] = f2b(gelu_f(v + bias)); }
          else { // EPI 6: Q cols 0-127 -> outB; K cols 128-255 -> dense kb; V cols 256-511 -> outB + vt
            int bb = r / 1025, tok = r - bb * 1025;
            if (col < 128){
              outB[(size_t)r * 512 + col] = f2b(v);
            } else if (col < 256){
              int hk = (col - 128) >> 4, dk = col & 15;
              outK[((size_t)((bb * 8 + hk) * 1032 + tok)) * 16 + dk] = f2b(v);
            } else {
              u16 bv = f2b(v);
              outB[(size_t)r * 512 + col] = bv;
              u16* vt = (u16*)outF;
              int hv = (col - 256) >> 5, dv = (col - 256) & 31;
              vt[((size_t)((bb * 8 + hv) * 32 + dv)) * 1032 + tok] = bv;
            }
          }
        }
      }
    }
  }
}

// ---------------- attention v9: swapped-QK^T register softmax, K-prefetch pipeline ----------------
__global__ __launch_bounds__(256) void k_attn(const u16* __restrict__ qkv,
    const u16* __restrict__ kb, const u16* __restrict__ vt,
    const float* __restrict__ pol, u16* __restrict__ o){
  __shared__ float pol_s[1088];
  __shared__ float oB[3][32][33];
  __shared__ float lsB[3][32];
  const int tid = threadIdx.x;
  const int lane = tid & 63, wv = tid >> 6;
  const int l32 = lane & 31, hi = lane >> 5;
  const int bid = blockIdx.x;
  const int xcd = bid & 7, idx = bid >> 3;
  const int bh = xcd * 8 + idx / 33, qt = idx % 33;
  const int b = bh >> 3, hh = bh & 7;
  const size_t rowbase = (size_t)b * 1025;
  const u16* kbh = kb + (size_t)bh * 1032 * 16;
  const int qg = qt * 32 + l32;
  const int qr = qg > 1024 ? 1024 : qg;
  const bf16x8 qf = *reinterpret_cast<const bf16x8*>(qkv + (rowbase + qr) * 512 + hh * 16 + hi * 8);
  float sqq = 0.f, scl = 0.f;
  {
    const bf16x8 kown = *reinterpret_cast<const bf16x8*>(kbh + (size_t)qr * 16 + hi * 8);
    const bf16x8 kcls = *reinterpret_cast<const bf16x8*>(kbh + (size_t)1024 * 16 + hi * 8);
    #pragma unroll
    for (int i = 0; i < 8; i++){
      sqq += (float)qf[i] * (float)kown[i];
      scl += (float)qf[i] * (float)kcls[i];
    }
    sqq += __shfl_xor(sqq, 32);
    scl += __shfl_xor(scl, 32);
  }
  const u16* vrow = vt + ((size_t)(bh * 32 + l32)) * 1032;
  const u16* krow = kbh + (size_t)((wv * 256) + l32) * 16 + hi * 8;
  for (int t = tid; t < 1088; t += 256){
    float p = (t <= 1024) ? pol[rowbase + t] : 0.f;
    pol_s[t] = (p > 0.f) ? __log2f(p) : -1.0e30f;
  }
  __syncthreads();

  float ls = 0.f;
  f32x16 oacc;
  #pragma unroll
  for (int r = 0; r < 16; r++) oacc[r] = 0.f;

  bf16x8 ka = *reinterpret_cast<const bf16x8*>(krow);
  #pragma unroll
  for (int s8 = 0; s8 < 8; s8++){
    const int jb32 = wv * 256 + s8 * 32;
    const bf16x8 ka_cur = ka;
    if (s8 < 7) ka = *reinterpret_cast<const bf16x8*>(krow + (size_t)(s8 + 1) * 512);
    const bf16x8 va0 = *reinterpret_cast<const bf16x8*>(vrow + jb32 + hi * 8);
    const bf16x8 va1 = *reinterpret_cast<const bf16x8*>(vrow + jb32 + 16 + hi * 8);
    f32x16 fz;
    #pragma unroll
    for (int r = 0; r < 16; r++) fz[r] = 0.f;
    f32x16 st = __builtin_amdgcn_mfma_f32_32x32x16_bf16(ka_cur, qf, fz, 0, 0, 0);
    float e[16];
    #pragma unroll
    for (int r = 0; r < 16; r++){
      int jg2 = jb32 + (r & 3) + 8 * (r >> 2) + 4 * hi;
      e[r] = exp2_(st[r] + pol_s[jg2]);
    }
    float s01 = (e[0] + e[1]) + (e[2] + e[3]);
    float s23 = (e[4] + e[5]) + (e[6] + e[7]);
    float s45 = (e[8] + e[9]) + (e[10] + e[11]);
    float s67 = (e[12] + e[13]) + (e[14] + e[15]);
    float psum = (s01 + s23) + (s45 + s67);
    psum += __shfl_xor(psum, 32);
    ls += psum;
    #pragma unroll
    for (int c = 0; c < 2; c++){
      u32 A0 = cvtpk(e[c*8+0], e[c*8+1]);
      u32 A1 = cvtpk(e[c*8+2], e[c*8+3]);
      u32 B0 = cvtpk(e[c*8+4], e[c*8+5]);
      u32 B1 = cvtpk(e[c*8+6], e[c*8+7]);
      u32 pA0 = __shfl_xor(A0, 32), pB0 = __shfl_xor(B0, 32);
      u32 pA1 = __shfl_xor(A1, 32), pB1 = __shfl_xor(B1, 32);
      u32x4 pw;
      pw.x = hi ? pB0 : A0;
      pw.y = hi ? pB1 : A1;
      pw.z = hi ? B0 : pA0;
      pw.w = hi ? B1 : pA1;
      bf16x8 pb = __builtin_bit_cast(bf16x8, pw);
      oacc = __builtin_amdgcn_mfma_f32_32x32x16_bf16(c == 0 ? va0 : va1, pb, oacc, 0, 0, 0);
    }
  }
  __syncthreads();
  if (wv > 0){
    lsB[wv-1][l32] = ls;
    #pragma unroll
    for (int r = 0; r < 16; r++) oB[wv-1][l32][(r & 3) + 8 * (r >> 2) + 4 * hi] = oacc[r];
  }
  __syncthreads();
  if (wv == 0 && qg <= 1024){
    float ls_t = (ls + lsB[0][l32]) + (lsB[1][l32] + lsB[2][l32]);
    const float pq = exp2_(pol_s[qg]);
    const float ec = (1.f - pq) * exp2_(sqq);
    const float ecl = exp2_(scl + pol_s[1024]);
    ls_t += ec + ecl;
    const float inv = 1.f / (ls_t + 1e-6f);
    u16* orow = o + (rowbase + qg) * 256 + hh * 32;
    const u16* vq   = qkv + (rowbase + qg) * 512 + 256 + hh * 32;
    const u16* vcls = qkv + (rowbase + 1024) * 512 + 256 + hh * 32;
    #pragma unroll
    for (int rq = 0; rq < 4; rq++){
      const int dv0 = 8 * rq + 4 * hi;
      const ushort4 vv4 = *reinterpret_cast<const ushort4*>(vq + dv0);
      const ushort4 vc4 = *reinterpret_cast<const ushort4*>(vcls + dv0);
      const u16* vv = (const u16*)&vv4;
      const u16* vc = (const u16*)&vc4;
      uint2 wout;
      u32* wp = &wout.x;
      #pragma unroll
      for (int j2 = 0; j2 < 2; j2++){
        const int d0 = dv0 + j2 * 2;
        float v0 = (oacc[rq*4 + j2*2    ] + oB[0][l32][d0    ] + oB[1][l32][d0    ] + oB[2][l32][d0    ]
                    + ec * b2f(vv[j2*2    ]) + ecl * b2f(vc[j2*2    ])) * inv;
        float v1 = (oacc[rq*4 + j2*2 + 1] + oB[0][l32][d0 + 1] + oB[1][l32][d0 + 1] + oB[2][l32][d0 + 1]
                    + ec * b2f(vv[j2*2 + 1]) + ecl * b2f(vc[j2*2 + 1])) * inv;
        wp[j2] = ((u32)f2b(v1) << 16) | (u32)f2b(v0);
      }
      *reinterpret_cast<uint2*>(orow + dv0) = wout;
    }
  }
}

// ---------------- host ----------------
extern "C" void kernel_launch(void* const* d_in, const int* in_sizes, int n_in,
                              void* d_out, int out_size, void* d_ws, size_t ws_size,
                              hipStream_t stream){
  const float* x    = (const float*)d_in[0];
  const float* pol  = (const float*)d_in[1];
  const float* c1w  = (const float*)d_in[2];
  const float* c2w  = (const float*)d_in[3];
  const float* bn1g = (const float*)d_in[4];
  const float* bn1b = (const float*)d_in[5];
  const float* bn1m = (const float*)d_in[6];
  const float* bn1v = (const float*)d_in[7];
  const float* bn2g = (const float*)d_in[8];
  const float* bn2b = (const float*)d_in[9];
  const float* bn2m = (const float*)d_in[10];
  const float* bn2v = (const float*)d_in[11];
  const float* cls  = (const float*)d_in[12];
  const float* ln1g = (const float*)d_in[13];
  const float* ln1b = (const float*)d_in[14];
  const float* ln2g = (const float*)d_in[15];
  const float* ln2b = (const float*)d_in[16];
  const float* wq   = (const float*)d_in[17];
  const float* wk   = (const float*)d_in[18];
  const float* wvp  = (const float*)d_in[19];
  const float* fcw  = (const float*)d_in[20];
  const float* ffw1 = (const float*)d_in[21];
  const float* ffb1 = (const float*)d_in[22];
  const float* ffw2 = (const float*)d_in[23];
  const float* ffb2 = (const float*)d_in[24];
  float* h = (float*)d_out;

  u16* ws   = (u16*)d_ws;
  u16* wc1  = ws;
  u16* wc2  = wc1  + 65536;
  u16* wqkv = wc2  + 65536;
  u16* wfc  = wqkv + 524288;
  u16* wff1 = wfc  + 262144;
  u16* wff2 = wff1 + 524288;
  u16* xT   = wff2 + 524288;
  u16* h1   = xT   + 2097152;
  u16* qkvb = h1   + 2097152;
  u16* ob   = qkvb + 4198400;
  u16* vtb  = ob   + 2099200;                // 64*32*1032 + slack
  u16* kbb  = vtb  + 2117632;                // 64*1032*16 = 1056768
  u16* ub   = qkvb;                          // alias: qkv dead after attention

  const float QSCALE = 0.25f * 1.4426950408889634f;  // 1/sqrt(DK) * log2(e), folded into wq
  SegPack sp;
  int b0 = 0;
  sp.s[0] = Seg{ c1w,  wc1,          65536,  65536,  0,      b0, 1.f }; b0 += 32;
  sp.s[1] = Seg{ c2w,  wc2,          65536,  65536,  0,      b0, 1.f }; b0 += 32;
  sp.s[2] = Seg{ wq,   wqkv,         131072, 32768,  131072, b0, QSCALE }; b0 += 64;
  sp.s[3] = Seg{ wk,   wqkv + 32768, 131072, 32768,  131072, b0, 1.f }; b0 += 64;
  sp.s[4] = Seg{ wvp,  wqkv + 65536, 262144, 65536,  131072, b0, 1.f }; b0 += 128;
  sp.s[5] = Seg{ fcw,  wfc,          262144, 262144, 0,      b0, 1.f }; b0 += 128;
  sp.s[6] = Seg{ ffw1, wff1,         524288, 524288, 0,      b0, 1.f }; b0 += 256;
  sp.s[7] = Seg{ ffw2, wff2,         524288, 524288, 0,      b0, 1.f }; b0 += 256;

  k_convert<<<b0, 256, 0, stream>>>(sp);
  k_transpose_x<<<dim3(32, 8, 8), 256, 0, stream>>>(x, xT);
  k_cls<<<1, 256, 0, stream>>>(cls, h);
  k_gemmT<1,64,64><<<8*16*4, 256, 0, stream>>>(xT, wc1, 8192, 256, 256, nullptr, h1,
                                               bn1g, bn1b, bn1m, bn1v);
  k_gemmT<2,64,64><<<8*16*4, 256, 0, stream>>>(h1, wc2, 8192, 256, 256, h, nullptr,
                                               bn2g, bn2b, bn2m, bn2v);
  for (int i = 0; i < 4; i++){
    k_gln<6><<<8*17*4, 256, 0, stream>>>(h, wqkv + i*131072, 8200, 512,
                                         ln1g + i*256, ln1b + i*256,
                                         (float*)vtb, qkvb, kbb, nullptr);
    k_attn<<<2112, 256, 0, stream>>>(qkvb, kbb, vtb, pol, ob);
    k_gemmT<3,64,64><<<8*17*4, 256, 0, stream>>>(ob, wfc + i*65536, 8200, 256, 256, h, nullptr,
                                                 nullptr, nullptr, nullptr, nullptr);
    k_gln<4><<<8*17*4, 256, 0, stream>>>(h, wff1 + i*131072, 8200, 512,
                                         ln2g + i*256, ln2b + i*256,
                                         nullptr, ub, nullptr, ffb1 + i*512);
    k_gemmT<5,64,64><<<8*17*4, 256, 0, stream>>>(ub, wff2 + i*131072, 8200, 512, 256, h, nullptr,
                                                 ffb2 + i*256, nullptr, nullptr, nullptr);
  }
}

// Round 13
// 357.859 us; speedup vs baseline: 1.2680x; 1.2680x over previous
//
#include <hip/hip_runtime.h>
#include <stdint.h>

// PCT forward: stem(conv1x1+BN+ReLU ×2) -> concat cls -> 4× [LN,QKV,attn,fc,LN,FF]
// B=8 C=256 N=1024 D=256 DK=16 DV=32 H=8 NB=4 P=1025, M_tok=8200

typedef unsigned short u16;
typedef unsigned int   u32;
typedef __bf16 bf16x8 __attribute__((ext_vector_type(8)));
typedef float  f32x4  __attribute__((ext_vector_type(4)));
typedef float  f32x16 __attribute__((ext_vector_type(16)));
typedef u32    u32x4  __attribute__((ext_vector_type(4)));

#define DEV static __device__ __forceinline__

DEV float b2f(u16 h){ u32 u = ((u32)h) << 16; return __builtin_bit_cast(float, u); }
DEV u16 f2b(float f){ u32 u = __builtin_bit_cast(u32, f); u32 r = (u + 0x7fffu + ((u >> 16) & 1u)) >> 16; return (u16)r; }
DEV float gelu_f(float x){ return 0.5f * x * (1.0f + erff(x * 0.7071067811865475f)); }
DEV u32 cvtpk(float lo, float hi){
  u32 w;
  asm("v_cvt_pk_bf16_f32 %0, %1, %2" : "=v"(w) : "v"(lo), "v"(hi));
  return w;
}
DEV float exp2_(float x){ float r; asm("v_exp_f32 %0, %1" : "=v"(r) : "v"(x)); return r; }

typedef void __attribute__((address_space(1)))* gas_t;
typedef void __attribute__((address_space(3)))* las_t;
DEV void cp16(const void* g, void* l){
  __builtin_amdgcn_global_load_lds((gas_t)(uintptr_t)g, (las_t)(uintptr_t)l, 16, 0, 0);
}

// ---------------- weight conversion f32 -> bf16 (with QKV concat, optional scale) ----------------
struct Seg { const float* src; u16* dst; int n; int period; int dstride; int block0; float scale; };
struct SegPack { Seg s[8]; };

__global__ __launch_bounds__(256) void k_convert(SegPack p){
  int bid = blockIdx.x;
  int si = 0;
  #pragma unroll
  for (int i = 1; i < 8; i++) if (bid >= p.s[i].block0) si = i;
  const Seg sg = p.s[si];
  int e0 = (bid - sg.block0) * 2048 + threadIdx.x * 8;
  #pragma unroll
  for (int k = 0; k < 8; k++){
    int e = e0 + k;
    if (e < sg.n) sg.dst[(e / sg.period) * sg.dstride + (e % sg.period)] = f2b(sg.src[e] * sg.scale);
  }
}

// ---------------- x [B,C,N] f32 -> xT [B,N,C] bf16 ----------------
__global__ __launch_bounds__(256) void k_transpose_x(const float* __restrict__ x, u16* __restrict__ xT){
  __shared__ float t[32][33];
  int b = blockIdx.z, ct = blockIdx.y, nt = blockIdx.x;
  int tx = threadIdx.x & 31, ty = threadIdx.x >> 5;
  const float* xp = x + ((size_t)b * 256 + ct * 32) * 1024 + nt * 32;
  #pragma unroll
  for (int k = 0; k < 4; k++) t[ty + 8*k][tx] = xp[(size_t)(ty + 8*k) * 1024 + tx];
  __syncthreads();
  u16* op = xT + ((size_t)b * 1024 + nt * 32) * 256 + ct * 32;
  #pragma unroll
  for (int k = 0; k < 4; k++) op[(size_t)(ty + 8*k) * 256 + tx] = f2b(t[tx][ty + 8*k]);
}

// ---------------- cls token row ----------------
__global__ void k_cls(const float* __restrict__ cls, float* __restrict__ h){
  int d = threadIdx.x;
  #pragma unroll
  for (int b = 0; b < 8; b++) h[(size_t)b * 1025 * 256 + d] = cls[d];
}

// ---------------- LayerNorm v2: 16 lanes/token, 4 tokens/wave, 4-step reduce ----------------
__global__ __launch_bounds__(256) void k_ln(const float* __restrict__ h, const float* __restrict__ g,
                                            const float* __restrict__ bt, u16* __restrict__ y){
  const int lane = threadIdx.x & 63, wv = threadIdx.x >> 6;
  const int l16 = lane & 15, ts = lane >> 4;
  const long t = (long)blockIdx.x * 16 + wv * 4 + ts;
  const bool valid = t < 8200;
  const long tl = valid ? t : 8199;
  const float* row = h + tl * 256;
  float4 v[4];
  #pragma unroll
  for (int c = 0; c < 4; c++) v[c] = *reinterpret_cast<const float4*>(row + c * 64 + l16 * 4);
  float s = 0.f, q = 0.f;
  #pragma unroll
  for (int c = 0; c < 4; c++){
    s += (v[c].x + v[c].y) + (v[c].z + v[c].w);
    q += (v[c].x*v[c].x + v[c].y*v[c].y) + (v[c].z*v[c].z + v[c].w*v[c].w);
  }
  #pragma unroll
  for (int o = 1; o < 16; o <<= 1){ s += __shfl_xor(s, o); q += __shfl_xor(q, o); }
  const float mean = s * (1.f/256.f);
  const float var  = q * (1.f/256.f) - mean * mean;
  const float rs = rsqrtf(var + 1e-5f);
  if (valid){
    u16* yrow = y + t * 256;
    #pragma unroll
    for (int c = 0; c < 4; c++){
      const float4 g4 = *reinterpret_cast<const float4*>(g  + c * 64 + l16 * 4);
      const float4 b4 = *reinterpret_cast<const float4*>(bt + c * 64 + l16 * 4);
      ushort4 ov;
      u16* o16 = (u16*)&ov;
      o16[0] = f2b((v[c].x - mean) * rs * g4.x + b4.x);
      o16[1] = f2b((v[c].y - mean) * rs * g4.y + b4.y);
      o16[2] = f2b((v[c].z - mean) * rs * g4.z + b4.z);
      o16[3] = f2b((v[c].w - mean) * rs * g4.w + b4.w);
      *reinterpret_cast<ushort4*>(yrow + c * 64 + l16 * 4) = ov;
    }
  }
}

// ---------------- NT GEMM BMxBN (bf16 A), 4 waves (2x2), XCD-pinned 1D grid ----------------
// bid -> xcd = bid&7; mi = xcd + 8*(rest % MT8); ni = rest / MT8.  Same m-tile always
// lands on the same XCD across n-rounds -> A panel stays in that XCD's L2.
// EPI: 1 bn+relu->bf16 | 2 bn+relu->f32 row-shifted | 3 f32 += | 4 (+bias,gelu)->bf16 |
//      5 f32 += (+bias) | 6 qkv: Q->outB, K->kb dense, V->outB + vt transposed
template<int EPI, int BM, int BN>
__global__ __launch_bounds__(256) void k_gemmT(const u16* __restrict__ A, const u16* __restrict__ W,
    int M, int K, int E, float* __restrict__ outF, u16* __restrict__ outB,
    u16* __restrict__ outK,
    const float* __restrict__ a0, const float* __restrict__ a1,
    const float* __restrict__ a2, const float* __restrict__ a3){
  constexpr int MR = BM / 32, NR = BN / 32;
  __shared__ __align__(16) u16 As[BM * 64];
  __shared__ __align__(16) u16 Bs[BN * 64];
  const int MTILES = (M + BM - 1) / BM;
  const int MT8 = (MTILES + 7) >> 3;
  const int bid = blockIdx.x;
  const int xcd = bid & 7, rest = bid >> 3;
  const int mi = xcd + 8 * (rest % MT8);
  const int ni = rest / MT8;
  if (mi >= MTILES) return;
  const int tM = mi * BM, tN = ni * BN;
  const int tid = threadIdx.x;
  const int lane = tid & 63, wv = tid >> 6;
  const int wr = wv >> 1, wc = wv & 1;
  f32x4 acc[MR][NR];
  #pragma unroll
  for (int m = 0; m < MR; m++)
    #pragma unroll
    for (int n = 0; n < NR; n++)
      #pragma unroll
      for (int j = 0; j < 4; j++) acc[m][n][j] = 0.f;

  const int l8 = lane >> 3, lm = lane & 7;
  for (int k0 = 0; k0 < K; k0 += 64){
    __syncthreads();
    #pragma unroll
    for (int is = 0; is < BM / 32; is++){
      int row = is * 32 + wv * 8 + l8;
      int kg = lm ^ (row & 7);
      int ra = tM + row; ra = ra < M ? ra : M - 1;
      cp16(A + (size_t)ra * K + k0 + kg * 8, As + is * 2048 + wv * 512);
    }
    #pragma unroll
    for (int is = 0; is < BN / 32; is++){
      int row = is * 32 + wv * 8 + l8;
      int kg = lm ^ (row & 7);
      cp16(W + (size_t)(tN + row) * K + k0 + kg * 8, Bs + is * 2048 + wv * 512);
    }
    __syncthreads();
    #pragma unroll
    for (int kk = 0; kk < 2; kk++){
      bf16x8 af[MR], bfv[NR];
      #pragma unroll
      for (int m = 0; m < MR; m++){
        int row = wr * (BM/2) + m * 16 + (lane & 15);
        int kg = (kk * 4 + (lane >> 4)) ^ (row & 7);
        af[m] = *reinterpret_cast<const bf16x8*>(&As[row * 64 + kg * 8]);
      }
      #pragma unroll
      for (int n = 0; n < NR; n++){
        int row = wc * (BN/2) + n * 16 + (lane & 15);
        int kg = (kk * 4 + (lane >> 4)) ^ (row & 7);
        bfv[n] = *reinterpret_cast<const bf16x8*>(&Bs[row * 64 + kg * 8]);
      }
      #pragma unroll
      for (int m = 0; m < MR; m++)
        #pragma unroll
        for (int n = 0; n < NR; n++)
          acc[m][n] = __builtin_amdgcn_mfma_f32_16x16x32_bf16(af[m], bfv[n], acc[m][n], 0, 0, 0);
    }
  }
  #pragma unroll
  for (int n = 0; n < NR; n++){
    const int col = tN + wc * (BN/2) + n * 16 + (lane & 15);
    float scale = 0.f, shift = 0.f, bias = 0.f;
    if (EPI == 1 || EPI == 2){
      float gv = a0[col], bv = a1[col], mv = a2[col], vv = a3[col];
      scale = gv * rsqrtf(vv + 1e-5f);
      shift = bv - mv * scale;
    }
    if (EPI == 4 || EPI == 5) bias = a0[col];
    #pragma unroll
    for (int m = 0; m < MR; m++){
      const int row0 = tM + wr * (BM/2) + m * 16 + ((lane >> 4) << 2);
      #pragma unroll
      for (int j = 0; j < 4; j++){
        int r = row0 + j;
        if (r < M){
          float v = acc[m][n][j];
          if (EPI == 1){ v = v * scale + shift; v = v > 0.f ? v : 0.f; outB[(size_t)r * E + col] = f2b(v); }
          else if (EPI == 2){ v = v * scale + shift; v = v > 0.f ? v : 0.f; outF[(size_t)(r + (r >> 10) + 1) * 256 + col] = v; }
          else if (EPI == 3){ outF[(size_t)r * E + col] += v; }
          else if (EPI == 4){ outB[(size_t)r * E + col] = f2b(gelu_f(v + bias)); }
          else if (EPI == 5){ outF[(size_t)r * E + col] += v + bias; }
          else { // EPI 6: Q cols 0-127 -> outB; K cols 128-255 -> dense kb; V cols 256-511 -> outB + vt
            int bb = r / 1025, tok = r - bb * 1025;
            if (col < 128){
              outB[(size_t)r * 512 + col] = f2b(v);
            } else if (col < 256){
              int hk = (col - 128) >> 4, dk = col & 15;
              outK[((size_t)((bb * 8 + hk) * 1032 + tok)) * 16 + dk] = f2b(v);
            } else {
              u16 bv = f2b(v);
              outB[(size_t)r * 512 + col] = bv;
              u16* vt = (u16*)outF;
              int hv = (col - 256) >> 5, dv = (col - 256) & 31;
              vt[((size_t)((bb * 8 + hv) * 32 + dv)) * 1032 + tok] = bv;
            }
          }
        }
      }
    }
  }
}

// ---------------- attention v9: v8b + explicit K-prefetch / early-V software pipeline ----------------
// 1D grid 2112 = 8 xcd * (8 bh * 33 qt). 4 waves, 4 tiles each (j 0..1023, no masking).
// cls column j=1024 handled in epilogue. ka[i+1] prefetched; va[i] issued before softmax.
__global__ __launch_bounds__(256) void k_attn(const u16* __restrict__ qkv,
    const u16* __restrict__ kb, const u16* __restrict__ vt,
    const float* __restrict__ pol, u16* __restrict__ o){
  __shared__ float pol_s[1088];
  __shared__ float oB[3][32][33];
  __shared__ float lsB[3][32];
  const int tid = threadIdx.x;
  const int lane = tid & 63, wv = tid >> 6;
  const int l32 = lane & 31, hi = lane >> 5;
  const int bid = blockIdx.x;
  const int xcd = bid & 7, idx = bid >> 3;
  const int bh = xcd * 8 + idx / 33, qt = idx % 33;
  const int b = bh >> 3, hh = bh & 7;
  const size_t rowbase = (size_t)b * 1025;
  const u16* kbh = kb + (size_t)bh * 1032 * 16;
  const int qg = qt * 32 + l32;
  const int qr = qg > 1024 ? 1024 : qg;
  const bf16x8 qf = *reinterpret_cast<const bf16x8*>(qkv + (rowbase + qr) * 512 + hh * 16 + hi * 8);
  // own-diagonal score and cls-column score (Q pre-scaled by 0.25*log2e)
  float sqq = 0.f, scl = 0.f;
  {
    const bf16x8 kown = *reinterpret_cast<const bf16x8*>(kbh + (size_t)qr * 16 + hi * 8);
    const bf16x8 kcls = *reinterpret_cast<const bf16x8*>(kbh + (size_t)1024 * 16 + hi * 8);
    #pragma unroll
    for (int i = 0; i < 8; i++){
      sqq += (float)qf[i] * (float)kown[i];
      scl += (float)qf[i] * (float)kcls[i];
    }
    sqq += __shfl_xor(sqq, 32);
    scl += __shfl_xor(scl, 32);
  }
  const u16* vrow = vt + ((size_t)(bh * 32 + l32)) * 1032;
  const u16* krow = kbh + (size_t)((wv * 256) + l32) * 16 + hi * 8;  // wave's first tile, this lane
  for (int t = tid; t < 1088; t += 256){
    float p = (t <= 1024) ? pol[rowbase + t] : 0.f;
    pol_s[t] = (p > 0.f) ? __log2f(p) : -1.0e30f;
  }
  __syncthreads();

  float ls = 0.f;
  f32x16 oacc;
  #pragma unroll
  for (int r = 0; r < 16; r++) oacc[r] = 0.f;

  // software pipeline: ka prefetched one 32-j sub ahead (stride 32 rows = 512 u16)
  bf16x8 ka = *reinterpret_cast<const bf16x8*>(krow);
  #pragma unroll
  for (int s8 = 0; s8 < 8; s8++){
    const int jb32 = wv * 256 + s8 * 32;
    const bf16x8 ka_cur = ka;
    if (s8 < 7) ka = *reinterpret_cast<const bf16x8*>(krow + (size_t)(s8 + 1) * 512);
    // early-issue V for this sub (used after softmax)
    const bf16x8 va0 = *reinterpret_cast<const bf16x8*>(vrow + jb32 + hi * 8);
    const bf16x8 va1 = *reinterpret_cast<const bf16x8*>(vrow + jb32 + 16 + hi * 8);
    f32x16 fz;
    #pragma unroll
    for (int r = 0; r < 16; r++) fz[r] = 0.f;
    f32x16 st = __builtin_amdgcn_mfma_f32_32x32x16_bf16(ka_cur, qf, fz, 0, 0, 0);
    float e[16];
    #pragma unroll
    for (int r = 0; r < 16; r++){
      int jg2 = jb32 + (r & 3) + 8 * (r >> 2) + 4 * hi;
      e[r] = exp2_(st[r] + pol_s[jg2]);
    }
    // tree-reduce psum (depth 4, independent adds)
    float s01 = (e[0] + e[1]) + (e[2] + e[3]);
    float s23 = (e[4] + e[5]) + (e[6] + e[7]);
    float s45 = (e[8] + e[9]) + (e[10] + e[11]);
    float s67 = (e[12] + e[13]) + (e[14] + e[15]);
    float psum = (s01 + s23) + (s45 + s67);
    psum += __shfl_xor(psum, 32);
    ls += psum;
    #pragma unroll
    for (int c = 0; c < 2; c++){
      u32 A0 = cvtpk(e[c*8+0], e[c*8+1]);
      u32 A1 = cvtpk(e[c*8+2], e[c*8+3]);
      u32 B0 = cvtpk(e[c*8+4], e[c*8+5]);
      u32 B1 = cvtpk(e[c*8+6], e[c*8+7]);
      u32 pA0 = __shfl_xor(A0, 32), pB0 = __shfl_xor(B0, 32);
      u32 pA1 = __shfl_xor(A1, 32), pB1 = __shfl_xor(B1, 32);
      u32x4 pw;
      pw.x = hi ? pB0 : A0;
      pw.y = hi ? pB1 : A1;
      pw.z = hi ? B0 : pA0;
      pw.w = hi ? B1 : pA1;
      bf16x8 pb = __builtin_bit_cast(bf16x8, pw);
      oacc = __builtin_amdgcn_mfma_f32_32x32x16_bf16(c == 0 ? va0 : va1, pb, oacc, 0, 0, 0);
    }
  }
  __syncthreads();
  if (wv > 0){
    lsB[wv-1][l32] = ls;
    #pragma unroll
    for (int r = 0; r < 16; r++) oB[wv-1][l32][(r & 3) + 8 * (r >> 2) + 4 * hi] = oacc[r];
  }
  __syncthreads();
  if (wv == 0 && qg <= 1024){
    float ls_t = (ls + lsB[0][l32]) + (lsB[1][l32] + lsB[2][l32]);
    const float pq = exp2_(pol_s[qg]);
    const float ec = (1.f - pq) * exp2_(sqq);          // diag: ap=1 instead of p_q
    const float ecl = exp2_(scl + pol_s[1024]);        // cls column j=1024
    ls_t += ec + ecl;
    const float inv = 1.f / (ls_t + 1e-6f);
    u16* orow = o + (rowbase + qg) * 256 + hh * 32;
    const u16* vq   = qkv + (rowbase + qg) * 512 + 256 + hh * 32;
    const u16* vcls = qkv + (rowbase + 1024) * 512 + 256 + hh * 32;
    #pragma unroll
    for (int rq = 0; rq < 4; rq++){
      const int dv0 = 8 * rq + 4 * hi;
      const ushort4 vv4 = *reinterpret_cast<const ushort4*>(vq + dv0);
      const ushort4 vc4 = *reinterpret_cast<const ushort4*>(vcls + dv0);
      const u16* vv = (const u16*)&vv4;
      const u16* vc = (const u16*)&vc4;
      uint2 wout;
      u32* wp = &wout.x;
      #pragma unroll
      for (int j2 = 0; j2 < 2; j2++){
        const int d0 = dv0 + j2 * 2;
        float v0 = (oacc[rq*4 + j2*2    ] + oB[0][l32][d0    ] + oB[1][l32][d0    ] + oB[2][l32][d0    ]
                    + ec * b2f(vv[j2*2    ]) + ecl * b2f(vc[j2*2    ])) * inv;
        float v1 = (oacc[rq*4 + j2*2 + 1] + oB[0][l32][d0 + 1] + oB[1][l32][d0 + 1] + oB[2][l32][d0 + 1]
                    + ec * b2f(vv[j2*2 + 1]) + ecl * b2f(vc[j2*2 + 1])) * inv;
        wp[j2] = ((u32)f2b(v1) << 16) | (u32)f2b(v0);
      }
      *reinterpret_cast<uint2*>(orow + dv0) = wout;
    }
  }
}

// ---------------- host ----------------
extern "C" void kernel_launch(void* const* d_in, const int* in_sizes, int n_in,
                              void* d_out, int out_size, void* d_ws, size_t ws_size,
                              hipStream_t stream){
  const float* x    = (const float*)d_in[0];
  const float* pol  = (const float*)d_in[1];
  const float* c1w  = (const float*)d_in[2];
  const float* c2w  = (const float*)d_in[3];
  const float* bn1g = (const float*)d_in[4];
  const float* bn1b = (const float*)d_in[5];
  const float* bn1m = (const float*)d_in[6];
  const float* bn1v = (const float*)d_in[7];
  const float* bn2g = (const float*)d_in[8];
  const float* bn2b = (const float*)d_in[9];
  const float* bn2m = (const float*)d_in[10];
  const float* bn2v = (const float*)d_in[11];
  const float* cls  = (const float*)d_in[12];
  const float* ln1g = (const float*)d_in[13];
  const float* ln1b = (const float*)d_in[14];
  const float* ln2g = (const float*)d_in[15];
  const float* ln2b = (const float*)d_in[16];
  const float* wq   = (const float*)d_in[17];
  const float* wk   = (const float*)d_in[18];
  const float* wvp  = (const float*)d_in[19];
  const float* fcw  = (const float*)d_in[20];
  const float* ffw1 = (const float*)d_in[21];
  const float* ffb1 = (const float*)d_in[22];
  const float* ffw2 = (const float*)d_in[23];
  const float* ffb2 = (const float*)d_in[24];
  float* h = (float*)d_out;

  u16* ws   = (u16*)d_ws;
  u16* wc1  = ws;
  u16* wc2  = wc1  + 65536;
  u16* wqkv = wc2  + 65536;
  u16* wfc  = wqkv + 524288;
  u16* wff1 = wfc  + 262144;
  u16* wff2 = wff1 + 524288;
  u16* xT   = wff2 + 524288;
  u16* h1   = xT   + 2097152;
  u16* yb   = h1   + 2097152;
  u16* qkvb = yb   + 2099200;
  u16* ob   = qkvb + 4198400;
  u16* vtb  = ob   + 2099200;                // 64*32*1032 + slack
  u16* kbb  = vtb  + 2117632;                // 64*1032*16 = 1056768
  u16* ub   = qkvb;                          // alias: qkv dead after attention

  const float QSCALE = 0.25f * 1.4426950408889634f;  // 1/sqrt(DK) * log2(e), folded into wq
  SegPack sp;
  int b0 = 0;
  sp.s[0] = Seg{ c1w,  wc1,          65536,  65536,  0,      b0, 1.f }; b0 += 32;
  sp.s[1] = Seg{ c2w,  wc2,          65536,  65536,  0,      b0, 1.f }; b0 += 32;
  sp.s[2] = Seg{ wq,   wqkv,         131072, 32768,  131072, b0, QSCALE }; b0 += 64;
  sp.s[3] = Seg{ wk,   wqkv + 32768, 131072, 32768,  131072, b0, 1.f }; b0 += 64;
  sp.s[4] = Seg{ wvp,  wqkv + 65536, 262144, 65536,  131072, b0, 1.f }; b0 += 128;
  sp.s[5] = Seg{ fcw,  wfc,          262144, 262144, 0,      b0, 1.f }; b0 += 128;
  sp.s[6] = Seg{ ffw1, wff1,         524288, 524288, 0,      b0, 1.f }; b0 += 256;
  sp.s[7] = Seg{ ffw2, wff2,         524288, 524288, 0,      b0, 1.f }; b0 += 256;

  k_convert<<<b0, 256, 0, stream>>>(sp);
  k_transpose_x<<<dim3(32, 8, 8), 256, 0, stream>>>(x, xT);
  k_cls<<<1, 256, 0, stream>>>(cls, h);
  // XCD-pinned 1D grids: 8 * MT8 * NT blocks.  M=8192: MT8=16; M=8200: MT8=17.
  k_gemmT<1,64,64><<<8*16*4, 256, 0, stream>>>(xT, wc1, 8192, 256, 256, nullptr, h1, nullptr,
                                               bn1g, bn1b, bn1m, bn1v);
  k_gemmT<2,64,64><<<8*16*4, 256, 0, stream>>>(h1, wc2, 8192, 256, 256, h, nullptr, nullptr,
                                               bn2g, bn2b, bn2m, bn2v);
  for (int i = 0; i < 4; i++){
    k_ln<<<513, 256, 0, stream>>>(h, ln1g + i*256, ln1b + i*256, yb);
    k_gemmT<6,64,128><<<8*17*4, 256, 0, stream>>>(yb, wqkv + i*131072, 8200, 256, 512,
                                                  (float*)vtb, qkvb, kbb,
                                                  nullptr, nullptr, nullptr, nullptr);
    k_attn<<<2112, 256, 0, stream>>>(qkvb, kbb, vtb, pol, ob);
    k_gemmT<3,64,64><<<8*17*4, 256, 0, stream>>>(ob, wfc + i*65536, 8200, 256, 256, h, nullptr, nullptr,
                                                 nullptr, nullptr, nullptr, nullptr);
    k_ln<<<513, 256, 0, stream>>>(h, ln2g + i*256, ln2b + i*256, yb);
    k_gemmT<4,64,128><<<8*17*4, 256, 0, stream>>>(yb, wff1 + i*131072, 8200, 256, 512, nullptr, ub, nullptr,
                                                  ffb1 + i*512, nullptr, nullptr, nullptr);
    k_gemmT<5,64,64><<<8*17*4, 256, 0, stream>>>(ub, wff2 + i*131072, 8200, 512, 256, h, nullptr, nullptr,
                                                 ffb2 + i*256, nullptr, nullptr, nullptr);
  }
}

// Round 14
// 350.032 us; speedup vs baseline: 1.2964x; 1.0224x over previous
//
#include <hip/hip_runtime.h>
#include <stdint.h>

// PCT forward: stem(conv1x1+BN+ReLU ×2) -> concat cls -> 4× [LN,QKV,attn,fc,LN,FF]
// B=8 C=256 N=1024 D=256 DK=16 DV=32 H=8 NB=4 P=1025, M_tok=8200

typedef unsigned short u16;
typedef unsigned int   u32;
typedef __bf16 bf16x8 __attribute__((ext_vector_type(8)));
typedef float  f32x4  __attribute__((ext_vector_type(4)));
typedef float  f32x16 __attribute__((ext_vector_type(16)));
typedef u32    u32x4  __attribute__((ext_vector_type(4)));

#define DEV static __device__ __forceinline__

DEV float b2f(u16 h){ u32 u = ((u32)h) << 16; return __builtin_bit_cast(float, u); }
DEV u16 f2b(float f){ u32 u = __builtin_bit_cast(u32, f); u32 r = (u + 0x7fffu + ((u >> 16) & 1u)) >> 16; return (u16)r; }
DEV float gelu_f(float x){ return 0.5f * x * (1.0f + erff(x * 0.7071067811865475f)); }
DEV u32 cvtpk(float lo, float hi){
  u32 w;
  asm("v_cvt_pk_bf16_f32 %0, %1, %2" : "=v"(w) : "v"(lo), "v"(hi));
  return w;
}
DEV float exp2_(float x){ float r; asm("v_exp_f32 %0, %1" : "=v"(r) : "v"(x)); return r; }

typedef void __attribute__((address_space(1)))* gas_t;
typedef void __attribute__((address_space(3)))* las_t;
DEV void cp16(const void* g, void* l){
  __builtin_amdgcn_global_load_lds((gas_t)(uintptr_t)g, (las_t)(uintptr_t)l, 16, 0, 0);
}

// ---------------- weight conversion f32 -> bf16 (with QKV concat, optional scale) ----------------
struct Seg { const float* src; u16* dst; int n; int period; int dstride; int block0; float scale; };
struct SegPack { Seg s[8]; };

__global__ __launch_bounds__(256) void k_convert(SegPack p){
  int bid = blockIdx.x;
  int si = 0;
  #pragma unroll
  for (int i = 1; i < 8; i++) if (bid >= p.s[i].block0) si = i;
  const Seg sg = p.s[si];
  int e0 = (bid - sg.block0) * 2048 + threadIdx.x * 8;
  #pragma unroll
  for (int k = 0; k < 8; k++){
    int e = e0 + k;
    if (e < sg.n) sg.dst[(e / sg.period) * sg.dstride + (e % sg.period)] = f2b(sg.src[e] * sg.scale);
  }
}

// ---------------- x [B,C,N] f32 -> xT [B,N,C] bf16 ----------------
__global__ __launch_bounds__(256) void k_transpose_x(const float* __restrict__ x, u16* __restrict__ xT){
  __shared__ float t[32][33];
  int b = blockIdx.z, ct = blockIdx.y, nt = blockIdx.x;
  int tx = threadIdx.x & 31, ty = threadIdx.x >> 5;
  const float* xp = x + ((size_t)b * 256 + ct * 32) * 1024 + nt * 32;
  #pragma unroll
  for (int k = 0; k < 4; k++) t[ty + 8*k][tx] = xp[(size_t)(ty + 8*k) * 1024 + tx];
  __syncthreads();
  u16* op = xT + ((size_t)b * 1024 + nt * 32) * 256 + ct * 32;
  #pragma unroll
  for (int k = 0; k < 4; k++) op[(size_t)(ty + 8*k) * 256 + tx] = f2b(t[tx][ty + 8*k]);
}

// ---------------- cls token row ----------------
__global__ void k_cls(const float* __restrict__ cls, float* __restrict__ h){
  int d = threadIdx.x;
  #pragma unroll
  for (int b = 0; b < 8; b++) h[(size_t)b * 1025 * 256 + d] = cls[d];
}

// ---------------- LayerNorm: h f32 -> y bf16 (wave per token) ----------------
__global__ __launch_bounds__(256) void k_ln(const float* __restrict__ h, const float* __restrict__ g,
                                            const float* __restrict__ bt, u16* __restrict__ y){
  int lane = threadIdx.x & 63, wv = threadIdx.x >> 6;
  long t = (long)blockIdx.x * 4 + wv;
  if (t >= 8200) return;
  const float* row = h + t * 256;
  float4 v = *reinterpret_cast<const float4*>(row + lane * 4);
  float s = v.x + v.y + v.z + v.w;
  float q = v.x*v.x + v.y*v.y + v.z*v.z + v.w*v.w;
  #pragma unroll
  for (int o = 32; o > 0; o >>= 1){ s += __shfl_xor(s, o); q += __shfl_xor(q, o); }
  float mean = s * (1.f/256.f);
  float var  = q * (1.f/256.f) - mean * mean;
  float rs = rsqrtf(var + 1e-5f);
  ushort4 ov;
  const float* vp = &v.x;
  u16* o16 = (u16*)&ov;
  #pragma unroll
  for (int j = 0; j < 4; j++){
    int c = lane * 4 + j;
    o16[j] = f2b((vp[j] - mean) * rs * g[c] + bt[c]);
  }
  *reinterpret_cast<ushort4*>(y + t * 256 + lane * 4) = ov;
}

// ---------------- NT GEMM BMxBN (bf16 A), 4 waves (2x2), XCD-pinned 1D grid ----------------
// bid -> xcd = bid&7; mi = xcd + 8*(rest % MT8); ni = rest / MT8.  Same m-tile always
// lands on the same XCD across n-rounds -> A panel stays in that XCD's L2.
// EPI: 1 bn+relu->bf16 | 2 bn+relu->f32 row-shifted | 3 f32 += | 4 (+bias,gelu)->bf16 |
//      5 f32 += (+bias) | 6 qkv: Q->outB, K->kb dense, V->outB + vt transposed
template<int EPI, int BM, int BN>
__global__ __launch_bounds__(256) void k_gemmT(const u16* __restrict__ A, const u16* __restrict__ W,
    int M, int K, int E, float* __restrict__ outF, u16* __restrict__ outB,
    u16* __restrict__ outK,
    const float* __restrict__ a0, const float* __restrict__ a1,
    const float* __restrict__ a2, const float* __restrict__ a3){
  constexpr int MR = BM / 32, NR = BN / 32;
  __shared__ __align__(16) u16 As[BM * 64];
  __shared__ __align__(16) u16 Bs[BN * 64];
  const int MTILES = (M + BM - 1) / BM;
  const int MT8 = (MTILES + 7) >> 3;
  const int bid = blockIdx.x;
  const int xcd = bid & 7, rest = bid >> 3;
  const int mi = xcd + 8 * (rest % MT8);
  const int ni = rest / MT8;
  if (mi >= MTILES) return;
  const int tM = mi * BM, tN = ni * BN;
  const int tid = threadIdx.x;
  const int lane = tid & 63, wv = tid >> 6;
  const int wr = wv >> 1, wc = wv & 1;
  f32x4 acc[MR][NR];
  #pragma unroll
  for (int m = 0; m < MR; m++)
    #pragma unroll
    for (int n = 0; n < NR; n++)
      #pragma unroll
      for (int j = 0; j < 4; j++) acc[m][n][j] = 0.f;

  const int l8 = lane >> 3, lm = lane & 7;
  for (int k0 = 0; k0 < K; k0 += 64){
    __syncthreads();
    #pragma unroll
    for (int is = 0; is < BM / 32; is++){
      int row = is * 32 + wv * 8 + l8;
      int kg = lm ^ (row & 7);
      int ra = tM + row; ra = ra < M ? ra : M - 1;
      cp16(A + (size_t)ra * K + k0 + kg * 8, As + is * 2048 + wv * 512);
    }
    #pragma unroll
    for (int is = 0; is < BN / 32; is++){
      int row = is * 32 + wv * 8 + l8;
      int kg = lm ^ (row & 7);
      cp16(W + (size_t)(tN + row) * K + k0 + kg * 8, Bs + is * 2048 + wv * 512);
    }
    __syncthreads();
    #pragma unroll
    for (int kk = 0; kk < 2; kk++){
      bf16x8 af[MR], bfv[NR];
      #pragma unroll
      for (int m = 0; m < MR; m++){
        int row = wr * (BM/2) + m * 16 + (lane & 15);
        int kg = (kk * 4 + (lane >> 4)) ^ (row & 7);
        af[m] = *reinterpret_cast<const bf16x8*>(&As[row * 64 + kg * 8]);
      }
      #pragma unroll
      for (int n = 0; n < NR; n++){
        int row = wc * (BN/2) + n * 16 + (lane & 15);
        int kg = (kk * 4 + (lane >> 4)) ^ (row & 7);
        bfv[n] = *reinterpret_cast<const bf16x8*>(&Bs[row * 64 + kg * 8]);
      }
      #pragma unroll
      for (int m = 0; m < MR; m++)
        #pragma unroll
        for (int n = 0; n < NR; n++)
          acc[m][n] = __builtin_amdgcn_mfma_f32_16x16x32_bf16(af[m], bfv[n], acc[m][n], 0, 0, 0);
    }
  }
  #pragma unroll
  for (int n = 0; n < NR; n++){
    const int col = tN + wc * (BN/2) + n * 16 + (lane & 15);
    float scale = 0.f, shift = 0.f, bias = 0.f;
    if (EPI == 1 || EPI == 2){
      float gv = a0[col], bv = a1[col], mv = a2[col], vv = a3[col];
      scale = gv * rsqrtf(vv + 1e-5f);
      shift = bv - mv * scale;
    }
    if (EPI == 4 || EPI == 5) bias = a0[col];
    #pragma unroll
    for (int m = 0; m < MR; m++){
      const int row0 = tM + wr * (BM/2) + m * 16 + ((lane >> 4) << 2);
      #pragma unroll
      for (int j = 0; j < 4; j++){
        int r = row0 + j;
        if (r < M){
          float v = acc[m][n][j];
          if (EPI == 1){ v = v * scale + shift; v = v > 0.f ? v : 0.f; outB[(size_t)r * E + col] = f2b(v); }
          else if (EPI == 2){ v = v * scale + shift; v = v > 0.f ? v : 0.f; outF[(size_t)(r + (r >> 10) + 1) * 256 + col] = v; }
          else if (EPI == 3){ outF[(size_t)r * E + col] += v; }
          else if (EPI == 4){ outB[(size_t)r * E + col] = f2b(gelu_f(v + bias)); }
          else if (EPI == 5){ outF[(size_t)r * E + col] += v + bias; }
          else { // EPI 6: Q cols 0-127 -> outB; K cols 128-255 -> dense kb; V cols 256-511 -> outB + vt
            int bb = r / 1025, tok = r - bb * 1025;
            if (col < 128){
              outB[(size_t)r * 512 + col] = f2b(v);
            } else if (col < 256){
              int hk = (col - 128) >> 4, dk = col & 15;
              outK[((size_t)((bb * 8 + hk) * 1032 + tok)) * 16 + dk] = f2b(v);
            } else {
              u16 bv = f2b(v);
              outB[(size_t)r * 512 + col] = bv;
              u16* vt = (u16*)outF;
              int hv = (col - 256) >> 5, dv = (col - 256) & 31;
              vt[((size_t)((bb * 8 + hv) * 32 + dv)) * 1032 + tok] = bv;
            }
          }
        }
      }
    }
  }
}

// ---------------- attention v10: v9 + s_setprio around MFMA clusters (T5) ----------------
// 1D grid 2112 = 8 xcd * (8 bh * 33 qt). 4 waves, 4 tiles each (j 0..1023, no masking).
// cls column j=1024 handled in epilogue. ka[i+1] prefetched; va[i] issued before softmax.
__global__ __launch_bounds__(256) void k_attn(const u16* __restrict__ qkv,
    const u16* __restrict__ kb, const u16* __restrict__ vt,
    const float* __restrict__ pol, u16* __restrict__ o){
  __shared__ float pol_s[1088];
  __shared__ float oB[3][32][33];
  __shared__ float lsB[3][32];
  const int tid = threadIdx.x;
  const int lane = tid & 63, wv = tid >> 6;
  const int l32 = lane & 31, hi = lane >> 5;
  const int bid = blockIdx.x;
  const int xcd = bid & 7, idx = bid >> 3;
  const int bh = xcd * 8 + idx / 33, qt = idx % 33;
  const int b = bh >> 3, hh = bh & 7;
  const size_t rowbase = (size_t)b * 1025;
  const u16* kbh = kb + (size_t)bh * 1032 * 16;
  const int qg = qt * 32 + l32;
  const int qr = qg > 1024 ? 1024 : qg;
  const bf16x8 qf = *reinterpret_cast<const bf16x8*>(qkv + (rowbase + qr) * 512 + hh * 16 + hi * 8);
  // own-diagonal score and cls-column score (Q pre-scaled by 0.25*log2e)
  float sqq = 0.f, scl = 0.f;
  {
    const bf16x8 kown = *reinterpret_cast<const bf16x8*>(kbh + (size_t)qr * 16 + hi * 8);
    const bf16x8 kcls = *reinterpret_cast<const bf16x8*>(kbh + (size_t)1024 * 16 + hi * 8);
    #pragma unroll
    for (int i = 0; i < 8; i++){
      sqq += (float)qf[i] * (float)kown[i];
      scl += (float)qf[i] * (float)kcls[i];
    }
    sqq += __shfl_xor(sqq, 32);
    scl += __shfl_xor(scl, 32);
  }
  const u16* vrow = vt + ((size_t)(bh * 32 + l32)) * 1032;
  const u16* krow = kbh + (size_t)((wv * 256) + l32) * 16 + hi * 8;  // wave's first tile, this lane
  for (int t = tid; t < 1088; t += 256){
    float p = (t <= 1024) ? pol[rowbase + t] : 0.f;
    pol_s[t] = (p > 0.f) ? __log2f(p) : -1.0e30f;
  }
  __syncthreads();

  float ls = 0.f;
  f32x16 oacc;
  #pragma unroll
  for (int r = 0; r < 16; r++) oacc[r] = 0.f;

  // software pipeline: ka prefetched one 32-j sub ahead (stride 32 rows = 512 u16)
  bf16x8 ka = *reinterpret_cast<const bf16x8*>(krow);
  #pragma unroll
  for (int s8 = 0; s8 < 8; s8++){
    const int jb32 = wv * 256 + s8 * 32;
    const bf16x8 ka_cur = ka;
    if (s8 < 7) ka = *reinterpret_cast<const bf16x8*>(krow + (size_t)(s8 + 1) * 512);
    // early-issue V for this sub (used after softmax)
    const bf16x8 va0 = *reinterpret_cast<const bf16x8*>(vrow + jb32 + hi * 8);
    const bf16x8 va1 = *reinterpret_cast<const bf16x8*>(vrow + jb32 + 16 + hi * 8);
    f32x16 fz;
    #pragma unroll
    for (int r = 0; r < 16; r++) fz[r] = 0.f;
    __builtin_amdgcn_s_setprio(1);
    f32x16 st = __builtin_amdgcn_mfma_f32_32x32x16_bf16(ka_cur, qf, fz, 0, 0, 0);
    __builtin_amdgcn_s_setprio(0);
    float e[16];
    #pragma unroll
    for (int r = 0; r < 16; r++){
      int jg2 = jb32 + (r & 3) + 8 * (r >> 2) + 4 * hi;
      e[r] = exp2_(st[r] + pol_s[jg2]);
    }
    // tree-reduce psum (depth 4, independent adds)
    float s01 = (e[0] + e[1]) + (e[2] + e[3]);
    float s23 = (e[4] + e[5]) + (e[6] + e[7]);
    float s45 = (e[8] + e[9]) + (e[10] + e[11]);
    float s67 = (e[12] + e[13]) + (e[14] + e[15]);
    float psum = (s01 + s23) + (s45 + s67);
    psum += __shfl_xor(psum, 32);
    ls += psum;
    u32x4 pw0, pw1;
    #pragma unroll
    for (int c = 0; c < 2; c++){
      u32 A0 = cvtpk(e[c*8+0], e[c*8+1]);
      u32 A1 = cvtpk(e[c*8+2], e[c*8+3]);
      u32 B0 = cvtpk(e[c*8+4], e[c*8+5]);
      u32 B1 = cvtpk(e[c*8+6], e[c*8+7]);
      u32 pA0 = __shfl_xor(A0, 32), pB0 = __shfl_xor(B0, 32);
      u32 pA1 = __shfl_xor(A1, 32), pB1 = __shfl_xor(B1, 32);
      u32x4 pw;
      pw.x = hi ? pB0 : A0;
      pw.y = hi ? pB1 : A1;
      pw.z = hi ? B0 : pA0;
      pw.w = hi ? B1 : pA1;
      if (c == 0) pw0 = pw; else pw1 = pw;
    }
    __builtin_amdgcn_s_setprio(1);
    oacc = __builtin_amdgcn_mfma_f32_32x32x16_bf16(va0, __builtin_bit_cast(bf16x8, pw0), oacc, 0, 0, 0);
    oacc = __builtin_amdgcn_mfma_f32_32x32x16_bf16(va1, __builtin_bit_cast(bf16x8, pw1), oacc, 0, 0, 0);
    __builtin_amdgcn_s_setprio(0);
  }
  __syncthreads();
  if (wv > 0){
    lsB[wv-1][l32] = ls;
    #pragma unroll
    for (int r = 0; r < 16; r++) oB[wv-1][l32][(r & 3) + 8 * (r >> 2) + 4 * hi] = oacc[r];
  }
  __syncthreads();
  if (wv == 0 && qg <= 1024){
    float ls_t = (ls + lsB[0][l32]) + (lsB[1][l32] + lsB[2][l32]);
    const float pq = exp2_(pol_s[qg]);
    const float ec = (1.f - pq) * exp2_(sqq);          // diag: ap=1 instead of p_q
    const float ecl = exp2_(scl + pol_s[1024]);        // cls column j=1024
    ls_t += ec + ecl;
    const float inv = 1.f / (ls_t + 1e-6f);
    u16* orow = o + (rowbase + qg) * 256 + hh * 32;
    const u16* vq   = qkv + (rowbase + qg) * 512 + 256 + hh * 32;
    const u16* vcls = qkv + (rowbase + 1024) * 512 + 256 + hh * 32;
    #pragma unroll
    for (int rq = 0; rq < 4; rq++){
      const int dv0 = 8 * rq + 4 * hi;
      const ushort4 vv4 = *reinterpret_cast<const ushort4*>(vq + dv0);
      const ushort4 vc4 = *reinterpret_cast<const ushort4*>(vcls + dv0);
      const u16* vv = (const u16*)&vv4;
      const u16* vc = (const u16*)&vc4;
      uint2 wout;
      u32* wp = &wout.x;
      #pragma unroll
      for (int j2 = 0; j2 < 2; j2++){
        const int d0 = dv0 + j2 * 2;
        float v0 = (oacc[rq*4 + j2*2    ] + oB[0][l32][d0    ] + oB[1][l32][d0    ] + oB[2][l32][d0    ]
                    + ec * b2f(vv[j2*2    ]) + ecl * b2f(vc[j2*2    ])) * inv;
        float v1 = (oacc[rq*4 + j2*2 + 1] + oB[0][l32][d0 + 1] + oB[1][l32][d0 + 1] + oB[2][l32][d0 + 1]
                    + ec * b2f(vv[j2*2 + 1]) + ecl * b2f(vc[j2*2 + 1])) * inv;
        wp[j2] = ((u32)f2b(v1) << 16) | (u32)f2b(v0);
      }
      *reinterpret_cast<uint2*>(orow + dv0) = wout;
    }
  }
}

// ---------------- host ----------------
extern "C" void kernel_launch(void* const* d_in, const int* in_sizes, int n_in,
                              void* d_out, int out_size, void* d_ws, size_t ws_size,
                              hipStream_t stream){
  const float* x    = (const float*)d_in[0];
  const float* pol  = (const float*)d_in[1];
  const float* c1w  = (const float*)d_in[2];
  const float* c2w  = (const float*)d_in[3];
  const float* bn1g = (const float*)d_in[4];
  const float* bn1b = (const float*)d_in[5];
  const float* bn1m = (const float*)d_in[6];
  const float* bn1v = (const float*)d_in[7];
  const float* bn2g = (const float*)d_in[8];
  const float* bn2b = (const float*)d_in[9];
  const float* bn2m = (const float*)d_in[10];
  const float* bn2v = (const float*)d_in[11];
  const float* cls  = (const float*)d_in[12];
  const float* ln1g = (const float*)d_in[13];
  const float* ln1b = (const float*)d_in[14];
  const float* ln2g = (const float*)d_in[15];
  const float* ln2b = (const float*)d_in[16];
  const float* wq   = (const float*)d_in[17];
  const float* wk   = (const float*)d_in[18];
  const float* wvp  = (const float*)d_in[19];
  const float* fcw  = (const float*)d_in[20];
  const float* ffw1 = (const float*)d_in[21];
  const float* ffb1 = (const float*)d_in[22];
  const float* ffw2 = (const float*)d_in[23];
  const float* ffb2 = (const float*)d_in[24];
  float* h = (float*)d_out;

  u16* ws   = (u16*)d_ws;
  u16* wc1  = ws;
  u16* wc2  = wc1  + 65536;
  u16* wqkv = wc2  + 65536;
  u16* wfc  = wqkv + 524288;
  u16* wff1 = wfc  + 262144;
  u16* wff2 = wff1 + 524288;
  u16* xT   = wff2 + 524288;
  u16* h1   = xT   + 2097152;
  u16* yb   = h1   + 2097152;
  u16* qkvb = yb   + 2099200;
  u16* ob   = qkvb + 4198400;
  u16* vtb  = ob   + 2099200;                // 64*32*1032 + slack
  u16* kbb  = vtb  + 2117632;                // 64*1032*16 = 1056768
  u16* ub   = qkvb;                          // alias: qkv dead after attention

  const float QSCALE = 0.25f * 1.4426950408889634f;  // 1/sqrt(DK) * log2(e), folded into wq
  SegPack sp;
  int b0 = 0;
  sp.s[0] = Seg{ c1w,  wc1,          65536,  65536,  0,      b0, 1.f }; b0 += 32;
  sp.s[1] = Seg{ c2w,  wc2,          65536,  65536,  0,      b0, 1.f }; b0 += 32;
  sp.s[2] = Seg{ wq,   wqkv,         131072, 32768,  131072, b0, QSCALE }; b0 += 64;
  sp.s[3] = Seg{ wk,   wqkv + 32768, 131072, 32768,  131072, b0, 1.f }; b0 += 64;
  sp.s[4] = Seg{ wvp,  wqkv + 65536, 262144, 65536,  131072, b0, 1.f }; b0 += 128;
  sp.s[5] = Seg{ fcw,  wfc,          262144, 262144, 0,      b0, 1.f }; b0 += 128;
  sp.s[6] = Seg{ ffw1, wff1,         524288, 524288, 0,      b0, 1.f }; b0 += 256;
  sp.s[7] = Seg{ ffw2, wff2,         524288, 524288, 0,      b0, 1.f }; b0 += 256;

  k_convert<<<b0, 256, 0, stream>>>(sp);
  k_transpose_x<<<dim3(32, 8, 8), 256, 0, stream>>>(x, xT);
  k_cls<<<1, 256, 0, stream>>>(cls, h);
  // XCD-pinned 1D grids: 8 * MT8 * NT blocks.  M=8192: MT8=16; M=8200: MT8=17.
  k_gemmT<1,64,64><<<8*16*4, 256, 0, stream>>>(xT, wc1, 8192, 256, 256, nullptr, h1, nullptr,
                                               bn1g, bn1b, bn1m, bn1v);
  k_gemmT<2,64,64><<<8*16*4, 256, 0, stream>>>(h1, wc2, 8192, 256, 256, h, nullptr, nullptr,
                                               bn2g, bn2b, bn2m, bn2v);
  for (int i = 0; i < 4; i++){
    k_ln<<<2050, 256, 0, stream>>>(h, ln1g + i*256, ln1b + i*256, yb);
    k_gemmT<6,64,128><<<8*17*4, 256, 0, stream>>>(yb, wqkv + i*131072, 8200, 256, 512,
                                                  (float*)vtb, qkvb, kbb,
                                                  nullptr, nullptr, nullptr, nullptr);
    k_attn<<<2112, 256, 0, stream>>>(qkvb, kbb, vtb, pol, ob);
    k_gemmT<3,64,64><<<8*17*4, 256, 0, stream>>>(ob, wfc + i*65536, 8200, 256, 256, h, nullptr, nullptr,
                                                 nullptr, nullptr, nullptr, nullptr);
    k_ln<<<2050, 256, 0, stream>>>(h, ln2g + i*256, ln2b + i*256, yb);
    k_gemmT<4,64,128><<<8*17*4, 256, 0, stream>>>(yb, wff1 + i*131072, 8200, 256, 512, nullptr, ub, nullptr,
                                                  ffb1 + i*512, nullptr, nullptr, nullptr);
    k_gemmT<5,64,64><<<8*17*4, 256, 0, stream>>>(ub, wff2 + i*131072, 8200, 512, 256, h, nullptr, nullptr,
                                                 ffb2 + i*256, nullptr, nullptr, nullptr);
  }
}